// Round 5
// baseline (213.118 us; speedup 1.0000x reference)
//
#include <hip/hip_runtime.h>
#include <stdint.h>

// Fully-fused binary conv, round 5.
// A: [32,64,112,112] f32, W: [64,64,3,3] f32 (flat), out: [32,64,112,112] f32.
// sign(x) bit = signbit(x); dot over 64 ch = 64 - 2*popc(a ^ w).
// Per block: 4 output rows x full width. Threads 0..167 pack the 6-row act tile
// (zero halo) into LDS while threads 168..447 pack weights into LDS; barrier;
// 64 threads build the 9x64 boundary-class base table; barrier; all 448 threads
// run conv (4 px x 16 o each), nontemporal float4 stores.
// out = bases[class][o] - 2*popc_sum (pad contribution folded into bases).

#define NN 32
#define CC 64
#define HH 112
#define WW 112
#define OO 64
#define HW (HH*WW)        // 12544
#define G4 (HW/4)         // 3136 quads per channel plane

#define BAND 4
#define NBAND (HH/BAND)   // 28
#define GRID (NN*NBAND)   // 896 blocks (3.5/CU)
#define BLK 448           // 7 waves

#define TROWS (BAND+2)    // 6 tile rows: image rows h0-1 .. h0+4
#define TCOLS 116         // 114 words used (1 halo + 112 + 1 halo), +2 pad

#define PACKT 168         // act-pack threads: 6 rows x 28 quads
#define WPT (BLK-PACKT)   // 280 weight-pack threads

typedef float f4v __attribute__((ext_vector_type(4)));

__global__ __launch_bounds__(BLK)
void fused_kernel(const float* __restrict__ act, const float* __restrict__ wgt,
                  float* __restrict__ out) {
    __shared__ uint64_t tile[TROWS][TCOLS];   // 5568 B packed act tile
    __shared__ uint64_t wlds[OO * 9];         // 4608 B packed weights
    __shared__ float bases[9][OO];            // 2304 B boundary-class bases

    const int b = blockIdx.x;
    const int n = b / NBAND;
    const int band = b - n * NBAND;
    const int h0 = band * BAND;
    const int tid = threadIdx.x;

    if (tid < PACKT) {
        // ---- pack activation tile: thread = (tile row tr, col quad tq) ----
        const int tr = tid / 28;
        const int tq = tid - tr * 28;
        const int h = h0 - 1 + tr;                // absolute image row
        uint64_t wd[4] = {0ull, 0ull, 0ull, 0ull};
        if ((unsigned)h < (unsigned)HH) {
            const uint4* bp = (const uint4*)act + (size_t)n * CC * G4
                            + (size_t)h * (WW / 4) + tq;
            uint32_t lo[4] = {0, 0, 0, 0}, hi[4] = {0, 0, 0, 0};
            #pragma unroll
            for (int c = 0; c < 64; ++c) {
                const uint4 v = bp[(size_t)c * G4];   // coalesced 16B across lanes
                const uint32_t s0 = v.x >> 31, s1 = v.y >> 31;
                const uint32_t s2 = v.z >> 31, s3 = v.w >> 31;
                if (c < 32) {
                    lo[0] |= s0 << c; lo[1] |= s1 << c;
                    lo[2] |= s2 << c; lo[3] |= s3 << c;
                } else {
                    const int cc = c - 32;
                    hi[0] |= s0 << cc; hi[1] |= s1 << cc;
                    hi[2] |= s2 << cc; hi[3] |= s3 << cc;
                }
            }
            wd[0] = ((uint64_t)hi[0] << 32) | lo[0];
            wd[1] = ((uint64_t)hi[1] << 32) | lo[1];
            wd[2] = ((uint64_t)hi[2] << 32) | lo[2];
            wd[3] = ((uint64_t)hi[3] << 32) | lo[3];
        }
        uint64_t* d = &tile[tr][1 + 4 * tq];      // tile col tc <-> image col tc-1
        d[0] = wd[0]; d[1] = wd[1]; d[2] = wd[2]; d[3] = wd[3];
        if (tq == 0)  tile[tr][0] = 0ull;         // left halo
        if (tq == 27) tile[tr][113] = 0ull;       // right halo
    } else {
        // ---- pack weights (concurrent with act pack) ----
        for (int t = tid - PACKT; t < OO * 9; t += WPT) {
            const int o = t / 9, k = t - o * 9;
            uint32_t lo = 0, hi = 0;
            #pragma unroll
            for (int i = 0; i < 64; ++i) {
                const uint32_t s = __float_as_uint(wgt[(o * 64 + i) * 9 + k]) >> 31;
                if (i < 32) lo |= s << i;
                else        hi |= s << (i - 32);
            }
            wlds[t] = ((uint64_t)hi << 32) | lo;
        }
    }

    __syncthreads();

    // ---- bases[class][o] = 576 - Sum_{k invalid in class}(64 - 2*popc(w_ok)) ----
    if (tid < OO) {
        const int o = tid;
        int contrib[9];
        #pragma unroll
        for (int k = 0; k < 9; ++k)
            contrib[k] = 64 - 2 * (int)__popcll(wlds[o * 9 + k]);
        #pragma unroll
        for (int ht = 0; ht < 3; ++ht) {
            #pragma unroll
            for (int wt = 0; wt < 3; ++wt) {
                int sum = 0;
                #pragma unroll
                for (int k = 0; k < 9; ++k) {
                    const int kh = k / 3, kw = k - kh * 3;
                    const bool inv = (ht == 0 && kh == 0) || (ht == 2 && kh == 2) ||
                                     (wt == 0 && kw == 0) || (wt == 2 && kw == 2);
                    if (inv) sum += contrib[k];
                }
                bases[ht * 3 + wt][o] = (float)(576 - sum);
            }
        }
    }

    __syncthreads();

    // ---- conv: thread = (o-group og, row r, col quad qc); 4 px x 16 o ----
    const int og = tid / 112;                    // 0..3
    const int q  = tid - og * 112;               // 0..111
    const int r  = q / 28;                       // 0..3 row within band
    const int qc = q - r * 28;                   // 0..27
    const int w0 = 4 * qc;
    const int h  = h0 + r;

    uint64_t A[3][6];                            // tile rows r..r+2, cols w0..w0+5
    #pragma unroll
    for (int rr = 0; rr < 3; ++rr) {
        #pragma unroll
        for (int j = 0; j < 6; ++j)
            A[rr][j] = tile[r + rr][w0 + j];
    }

    const int ht = (h == 0) ? 0 : ((h == HH - 1) ? 2 : 1);
    const float* bp0  = bases[ht * 3 + ((w0 == 0) ? 0 : 1)];
    const float* bp12 = bases[ht * 3 + 1];
    const float* bp3  = bases[ht * 3 + ((w0 + 3 == WW - 1) ? 2 : 1)];

    float* op = out + (size_t)n * (OO * HW) + (size_t)h * WW + w0;
    const int o0 = og * 16;
    #pragma unroll 2
    for (int o = o0; o < o0 + 16; ++o) {
        const uint64_t* wk = &wlds[o * 9];
        int s0 = 0, s1 = 0, s2 = 0, s3 = 0;
        #pragma unroll
        for (int kh = 0; kh < 3; ++kh) {
            #pragma unroll
            for (int kw = 0; kw < 3; ++kw) {
                const uint64_t wv = wk[kh * 3 + kw];
                // px j tap kw -> image col w0+j+kw-1 -> tile col w0+j+kw
                s0 += __popcll(A[kh][kw    ] ^ wv);
                s1 += __popcll(A[kh][kw + 1] ^ wv);
                s2 += __popcll(A[kh][kw + 2] ^ wv);
                s3 += __popcll(A[kh][kw + 3] ^ wv);
            }
        }
        f4v v;
        v.x = bp0[o]  - 2.0f * (float)s0;
        v.y = bp12[o] - 2.0f * (float)s1;
        v.z = bp12[o] - 2.0f * (float)s2;
        v.w = bp3[o]  - 2.0f * (float)s3;
        __builtin_nontemporal_store(v, (f4v*)(op + (size_t)o * HW));  // never re-read
    }
}

extern "C" void kernel_launch(void* const* d_in, const int* in_sizes, int n_in,
                              void* d_out, int out_size, void* d_ws, size_t ws_size,
                              hipStream_t stream) {
    const float* act = (const float*)d_in[0];
    const float* wgt = (const float*)d_in[1];
    float* out = (float*)d_out;
    fused_kernel<<<GRID, BLK, 0, stream>>>(act, wgt, out);
}

// Round 7
// 208.276 us; speedup vs baseline: 1.0232x; 1.0232x over previous
//
#include <hip/hip_runtime.h>
#include <stdint.h>

// Fused binary conv, round 7 = R5 structure minus its two measured flaws:
//  (1) weights+bases precomputed ONCE by a tiny kernel (R5 re-read 147KB f32
//      weights per block - as much traffic as its whole act tile);
//  (2) act pack uses ALL 448 threads (R5 used 168): item = (row, ch-eighth,
//      quad), 3 items x 8 independent uint4 loads per thread, partial 8-bit
//      sign masks to an LDS byte matrix; u64 word = 8 consecutive bytes.
// Conv phase is verbatim R5 (harness-verified correct).
// sign(x) bit = signbit(x); dot over 64 ch = 64 - 2*popc(a ^ w); zero halo
// (bits 0 = all +1) with pad contribution folded into bases[class][o].

#define NN 32
#define CC 64
#define HH 112
#define WW 112
#define OO 64
#define HW (HH*WW)        // 12544
#define G4 (HW/4)         // 3136 quads per channel plane

#define BAND 4
#define NBAND (HH/BAND)   // 28
#define GRID (NN*NBAND)   // 896 blocks
#define BLK 448           // 7 waves

#define TROWS (BAND+2)    // 6 tile rows: image rows h0-1 .. h0+4
#define TCOLS 116

typedef float f4v __attribute__((ext_vector_type(4)));

// workspace (u64 words): [0,576) wp | [1024,1312) basesg (f32[9][64])

__global__ __launch_bounds__(576)
void prepack_kernel(const float* __restrict__ wgt, uint64_t* __restrict__ wp,
                    float* __restrict__ basesg) {
    __shared__ uint64_t wl[OO * 9];
    const int t = threadIdx.x;                   // 0..575
    {
        const int o = t / 9, k = t - o * 9;
        uint32_t lo = 0, hi = 0;
        #pragma unroll
        for (int i = 0; i < 64; ++i) {
            const uint32_t s = __float_as_uint(wgt[(o * 64 + i) * 9 + k]) >> 31;
            if (i < 32) lo |= s << i;
            else        hi |= s << (i - 32);
        }
        const uint64_t w = ((uint64_t)hi << 32) | lo;
        wl[t] = w;
        wp[t] = w;
    }
    __syncthreads();
    if (t < OO) {
        const int o = t;
        int contrib[9];
        #pragma unroll
        for (int k = 0; k < 9; ++k)
            contrib[k] = 64 - 2 * (int)__popcll(wl[o * 9 + k]);
        #pragma unroll
        for (int ht = 0; ht < 3; ++ht) {
            #pragma unroll
            for (int wt = 0; wt < 3; ++wt) {
                int sum = 0;
                #pragma unroll
                for (int k = 0; k < 9; ++k) {
                    const int kh = k / 3, kw = k - kh * 3;
                    const bool inv = (ht == 0 && kh == 0) || (ht == 2 && kh == 2) ||
                                     (wt == 0 && kw == 0) || (wt == 2 && kw == 2);
                    if (inv) sum += contrib[k];
                }
                basesg[(ht * 3 + wt) * OO + o] = (float)(576 - sum);
            }
        }
    }
}

__global__ __launch_bounds__(BLK)
void fused_kernel(const float* __restrict__ act, const uint64_t* __restrict__ wp,
                  const float* __restrict__ basesg, float* __restrict__ out) {
    __shared__ uint64_t tile[TROWS][TCOLS];      // 5568 B packed act tile
    __shared__ uint8_t  sm[TROWS][112][8];       // 5376 B partial sign bytes
    __shared__ uint64_t wlds[OO * 9];            // 4608 B packed weights
    __shared__ float    basesl[9 * OO];          // 2304 B

    const int b = blockIdx.x;
    const int n = b / NBAND;
    const int band = b - n * NBAND;
    const int h0 = band * BAND;
    const int tid = threadIdx.x;

    // ---- copy precomputed tables (L2-resident, ~7KB) ----
    for (int t2 = tid; t2 < OO * 9; t2 += BLK) {
        wlds[t2] = wp[t2];
        basesl[t2] = basesg[t2];
    }

    // ---- pack act tile: 3 items/thread, item = (row r, eighth e, quad q) ----
    #pragma unroll
    for (int it = 0; it < 3; ++it) {
        const int item = tid + it * BLK;         // 0..1343
        const int r = item / 224;                // 0..5 tile row
        const int rem = item - r * 224;
        const int e = rem / 28;                  // 0..7 channel-eighth
        const int q = rem - e * 28;              // 0..27 quad
        const int h = h0 - 1 + r;                // absolute image row
        uint32_t b0 = 0, b1 = 0, b2 = 0, b3 = 0;
        if ((unsigned)h < (unsigned)HH) {
            const uint4* bp = (const uint4*)act
                            + ((size_t)n * CC + e * 8) * G4 + (size_t)h * 28 + q;
            #pragma unroll
            for (int j = 0; j < 8; ++j) {        // 8 independent 16B loads
                const uint4 v = bp[(size_t)j * G4];
                b0 |= (v.x >> 31) << j;
                b1 |= (v.y >> 31) << j;
                b2 |= (v.z >> 31) << j;
                b3 |= (v.w >> 31) << j;
            }
        }
        sm[r][4 * q + 0][e] = (uint8_t)b0;       // byte e = channels 8e..8e+7
        sm[r][4 * q + 1][e] = (uint8_t)b1;
        sm[r][4 * q + 2][e] = (uint8_t)b2;
        sm[r][4 * q + 3][e] = (uint8_t)b3;
    }

    __syncthreads();

    // ---- assemble u64 words (little-endian: byte e -> bits 8e..8e+7) ----
    if (tid < 224) {
        #pragma unroll
        for (int it = 0; it < 3; ++it) {
            const int wid = tid + it * 224;      // 0..671
            const int r = wid / 112;
            const int x = wid - r * 112;         // image col
            tile[r][x + 1] = *(const uint64_t*)sm[r][x];   // 8B-aligned LDS read
        }
    }
    if (tid < TROWS) { tile[tid][0] = 0ull; tile[tid][113] = 0ull; }  // side halo

    __syncthreads();

    // ---- conv (verbatim R5): thread = (og, r, qc); 4 px x 16 o ----
    const int og = tid / 112;                    // 0..3
    const int q  = tid - og * 112;               // 0..111
    const int r  = q / 28;                       // 0..3 row within band
    const int qc = q - r * 28;                   // 0..27
    const int w0 = 4 * qc;
    const int h  = h0 + r;

    uint64_t A[3][6];                            // tile rows r..r+2, cols w0..w0+5
    #pragma unroll
    for (int rr = 0; rr < 3; ++rr) {
        #pragma unroll
        for (int j = 0; j < 6; ++j)
            A[rr][j] = tile[r + rr][w0 + j];
    }

    const int ht = (h == 0) ? 0 : ((h == HH - 1) ? 2 : 1);
    const float* bp0  = &basesl[(ht * 3 + ((w0 == 0) ? 0 : 1)) * OO];
    const float* bp12 = &basesl[(ht * 3 + 1) * OO];
    const float* bp3  = &basesl[(ht * 3 + ((w0 + 3 == WW - 1) ? 2 : 1)) * OO];

    float* op = out + (size_t)n * (OO * HW) + (size_t)h * WW + w0;
    const int o0 = og * 16;
    #pragma unroll 2
    for (int o = o0; o < o0 + 16; ++o) {
        const uint64_t* wk = &wlds[o * 9];
        int s0 = 0, s1 = 0, s2 = 0, s3 = 0;
        #pragma unroll
        for (int kh = 0; kh < 3; ++kh) {
            #pragma unroll
            for (int kw = 0; kw < 3; ++kw) {
                const uint64_t wv = wk[kh * 3 + kw];
                // px j tap kw -> image col w0+j+kw-1 -> tile col w0+j+kw
                s0 += __popcll(A[kh][kw    ] ^ wv);
                s1 += __popcll(A[kh][kw + 1] ^ wv);
                s2 += __popcll(A[kh][kw + 2] ^ wv);
                s3 += __popcll(A[kh][kw + 3] ^ wv);
            }
        }
        f4v v;
        v.x = bp0[o]  - 2.0f * (float)s0;
        v.y = bp12[o] - 2.0f * (float)s1;
        v.z = bp12[o] - 2.0f * (float)s2;
        v.w = bp3[o]  - 2.0f * (float)s3;
        __builtin_nontemporal_store(v, (f4v*)(op + (size_t)o * HW));  // never re-read
    }
}

extern "C" void kernel_launch(void* const* d_in, const int* in_sizes, int n_in,
                              void* d_out, int out_size, void* d_ws, size_t ws_size,
                              hipStream_t stream) {
    const float* act = (const float*)d_in[0];
    const float* wgt = (const float*)d_in[1];
    float* out = (float*)d_out;

    uint64_t* wp = (uint64_t*)d_ws;              // 576 u64
    float* basesg = (float*)(wp + 1024);         // 576 f32

    prepack_kernel<<<1, 576, 0, stream>>>(wgt, wp, basesg);
    fused_kernel<<<GRID, BLK, 0, stream>>>(act, wp, basesg, out);
}